// Round 1
// 192.241 us; speedup vs baseline: 1.0530x; 1.0530x over previous
//
#include <hip/hip_runtime.h>
#include <hip/hip_bf16.h>
#include <math.h>

#define NB 2
#define NH 16
#define NS 2048
#define ND 128

typedef __bf16 bf16x8 __attribute__((ext_vector_type(8)));
typedef __bf16 bf16x4 __attribute__((ext_vector_type(4)));
typedef float f32x4 __attribute__((ext_vector_type(4)));

// ---------------------------------------------------------------------------
// Prepass: build the exact LDS images fa_fwd consumes, once per element.
//   Kb: [bh][jt][r=0..63]   rows of 256B; 16B slot s holds logical granule
//       c8 = s ^ (r&7)   (XOR swizzle -> conflict-free ds_read_b128)
//   Vb: [bh][jt][d=0..127] rows of 128B (V TRANSPOSED); 16B slot s holds
//       kv-granule g8 = s ^ (d&7)
// Each tile is 16KB, contiguous -> staged by linear global_load_lds.
// ---------------------------------------------------------------------------
__global__ __launch_bounds__(256)
void prep(const float* __restrict__ K, const float* __restrict__ V,
          char* __restrict__ Kb, char* __restrict__ Vb)
{
    int g = blockIdx.x * 256 + threadIdx.x;
    if (g < (1 << 20)) {
        // ---- K: one 16B output granule per thread ----
        const int c8 = g & 15;
        const int row = g >> 4;              // bh*2048 + s
        const int s = row & 2047, bh = row >> 11;
        const int jt = s >> 6, r = s & 63;
        const float* src = K + ((size_t)row << 7) + (c8 << 3);
        float4 a = *(const float4*)src;
        float4 c = *(const float4*)(src + 4);
        bf16x8 o;
        o[0]=(__bf16)a.x; o[1]=(__bf16)a.y; o[2]=(__bf16)a.z; o[3]=(__bf16)a.w;
        o[4]=(__bf16)c.x; o[5]=(__bf16)c.y; o[6]=(__bf16)c.z; o[7]=(__bf16)c.w;
        *(bf16x8*)(Kb + (((size_t)(bh*32 + jt)) << 14) + r*256 + ((c8 ^ (r & 7)) << 4)) = o;
    } else {
        // ---- V: transpose + swizzle, one 16B granule (8 kv of one d) ----
        g -= (1 << 20);
        const int t   = g >> 10;             // bh*32 + jt
        const int off = g & 1023;
        const int d = off >> 3, sl = off & 7;
        const int g8 = sl ^ (d & 7);
        const int bh = t >> 5, jt = t & 31;
        const float* src = V + (((size_t)(bh*2048 + jt*64 + g8*8)) << 7) + d;
        bf16x8 o;
        #pragma unroll
        for (int j = 0; j < 8; ++j) o[j] = (__bf16)src[(size_t)j << 7];
        *(bf16x8*)(Vb + (((size_t)t) << 14) + d*128 + (sl << 4)) = o;
    }
}

// ---------------------------------------------------------------------------
// Main kernel.  512 uniform blocks (bh x complementary q-tile pairs, 33 KV
// tiles each).  Double-buffered K/V staged via global_load_lds (bf16, already
// swizzled in global memory), counted vmcnt so next-tile loads cross the
// barrier.  QK^T computed SWAPPED (S^T = mfma(K,Q)) so P packs into b64
// stores; row sums kept in registers (no ones-row).
// ---------------------------------------------------------------------------
__device__ __forceinline__ void gld16(void* lds, const void* gsrc)
{
    __builtin_amdgcn_global_load_lds(
        (const __attribute__((address_space(1))) void*)gsrc,
        (__attribute__((address_space(3))) void*)lds, 16, 0, 0);
}

__global__ __launch_bounds__(256, 2)
void fa_fwd(const float* __restrict__ Qg_, const char* __restrict__ Kb,
            const char* __restrict__ Vb, float* __restrict__ Out)
{
    __shared__ __bf16 Kl[2][8192];   // 64 rows x 256B, swizzled
    __shared__ __bf16 Vl[2][8192];   // 128 rows x 128B, swizzled (V^T)
    __shared__ __bf16 Pl[4][1024];   // per-wave 16 rows x 128B, swizzled

    const int tid  = threadIdx.x;
    const int w    = tid >> 6;
    const int lane = tid & 63;
    const int quad = lane >> 4;
    const int l15  = lane & 15;

    const int pr = blockIdx.x >> 5;
    const int bh = blockIdx.x & 31;
    const int b  = bh >> 4, h = bh & 15;
    const int qtA = 31 - pr, qtB = pr;
    const int ntA = qtA + 1;
    const int total = ntA + qtB + 1;     // always 33
    const int qA = qtA * 64, qB = qtB * 64;

    const float* Qg = Qg_ + (size_t)bh * NS * ND;
    const char*  Kt = Kb + ((size_t)bh << 19);
    const char*  Vt = Vb + ((size_t)bh << 19);

    const int xo = (l15 & 7) << 4;       // XOR byte offset for 16B slots

    // ---- Q fragments for both phases (scaled), identical layout to before ----
    const float CSC = 0.08838834764831845f * 1.4426950408889634f;
    bf16x8 qfA[4], qfB[4], qcur[4];
    {
        const float* qp  = Qg + (size_t)(qA + 16*w + l15) * ND + quad*8;
        const float* qp2 = Qg + (size_t)(qB + 16*w + l15) * ND + quad*8;
        #pragma unroll
        for (int ks = 0; ks < 4; ++ks) {
            float4 a = *(const float4*)(qp + ks*32);
            float4 c = *(const float4*)(qp + ks*32 + 4);
            bf16x8 f;
            f[0]=(__bf16)(a.x*CSC); f[1]=(__bf16)(a.y*CSC); f[2]=(__bf16)(a.z*CSC); f[3]=(__bf16)(a.w*CSC);
            f[4]=(__bf16)(c.x*CSC); f[5]=(__bf16)(c.y*CSC); f[6]=(__bf16)(c.z*CSC); f[7]=(__bf16)(c.w*CSC);
            qfA[ks] = f;
            float4 a2 = *(const float4*)(qp2 + ks*32);
            float4 c2 = *(const float4*)(qp2 + ks*32 + 4);
            bf16x8 f2;
            f2[0]=(__bf16)(a2.x*CSC); f2[1]=(__bf16)(a2.y*CSC); f2[2]=(__bf16)(a2.z*CSC); f2[3]=(__bf16)(a2.w*CSC);
            f2[4]=(__bf16)(c2.x*CSC); f2[5]=(__bf16)(c2.y*CSC); f2[6]=(__bf16)(c2.z*CSC); f2[7]=(__bf16)(c2.w*CSC);
            qfB[ks] = f2;
        }
    }
    #pragma unroll
    for (int ks = 0; ks < 4; ++ks) qcur[ks] = qfA[ks];

    f32x4 O[8];
    #pragma unroll
    for (int dt = 0; dt < 8; ++dt)
        #pragma unroll
        for (int r = 0; r < 4; ++r) O[dt][r] = 0.0f;
    float rs = 0.0f;                     // per-lane partial row sum (q = base+16w+l15)

    char* const klds0 = (char*)&Kl[0][0];
    char* const vlds0 = (char*)&Vl[0][0];
    char* const Pw    = (char*)&Pl[w][0];

    auto stage = [&](int jt, int buf) {
        const char* kg = Kt + (((size_t)jt) << 14) + w*4096 + lane*16;
        const char* vg = Vt + (((size_t)jt) << 14) + w*4096 + lane*16;
        char* kl = klds0 + buf*16384 + w*4096;   // wave-uniform LDS base
        char* vl = vlds0 + buf*16384 + w*4096;
        #pragma unroll
        for (int i = 0; i < 4; ++i) {
            gld16(kl + i*1024, kg + i*1024);
            gld16(vl + i*1024, vg + i*1024);
        }
    };

    auto flush = [&](int qb) {
        float s1 = rs + __shfl_xor(rs, 16, 64);
        float s2 = s1 + __shfl_xor(s1, 32, 64);   // total row sum, all quads
        #pragma unroll
        for (int r = 0; r < 4; ++r) {
            float lsum = __shfl(s2, quad*4 + r, 64);
            float inv = 1.0f / lsum;
            int q = qb + 16*w + quad*4 + r;
            float* op = Out + ((size_t)(b*NS + q)) * (NH*ND) + h*ND + l15;
            #pragma unroll
            for (int dt = 0; dt < 8; ++dt)
                op[dt*16] = O[dt][r] * inv;
        }
    };

    stage(0, 0);                         // prefetch tile 0 (phase A)
    int cur = 0;

    for (int t = 0; t < total; ++t) {
        const int phase = (t >= ntA);
        const bool diag = (phase ? (t - ntA) == qtB : t == qtA);

        if (t + 1 < total) {
            const int jt2 = (t + 1 >= ntA) ? (t + 1 - ntA) : (t + 1);
            stage(jt2, cur ^ 1);
            asm volatile("s_waitcnt vmcnt(8)" ::: "memory");  // tile t landed; t+1 in flight
        } else {
            asm volatile("s_waitcnt vmcnt(0)" ::: "memory");
        }
        __builtin_amdgcn_s_barrier();
        asm volatile("" ::: "memory");

        if (t == ntA) {                  // phase switch: flush A, reset, swap Q
            flush(qA);
            rs = 0.0f;
            #pragma unroll
            for (int dt = 0; dt < 8; ++dt)
                #pragma unroll
                for (int r = 0; r < 4; ++r) O[dt][r] = 0.0f;
            #pragma unroll
            for (int ks = 0; ks < 4; ++ks) qcur[ks] = qfB[ks];
        }

        // ---- S^T = K Q^T : mfma(A=K-frag, B=Q-frag); lane owns col q=l15 ----
        const char* Kc = klds0 + cur*16384;
        f32x4 Sf[4];
        #pragma unroll
        for (int n = 0; n < 4; ++n)
            #pragma unroll
            for (int r = 0; r < 4; ++r) Sf[n][r] = 0.0f;
        #pragma unroll
        for (int ks = 0; ks < 4; ++ks) {
            bf16x8 kf[4];
            #pragma unroll
            for (int n = 0; n < 4; ++n)
                kf[n] = *(const bf16x8*)(Kc + (n*16 + l15)*256 + ((((ks*4 + quad) << 4)) ^ xo));
            #pragma unroll
            for (int n = 0; n < 4; ++n)
                Sf[n] = __builtin_amdgcn_mfma_f32_16x16x32_bf16(kf[n], qcur[ks], Sf[n], 0, 0, 0);
        }

        // ---- mask + exp2 -> packed P (b64 stores), accumulate row sum ----
        #pragma unroll
        for (int n = 0; n < 4; ++n) {
            bf16x4 pk;
            #pragma unroll
            for (int r = 0; r < 4; ++r) {
                float e = exp2f(Sf[n][r]);
                if (diag) {
                    // diag tile: kv base == q-tile base -> compare tile-local
                    int kvg = n*16 + quad*4 + r;
                    int qg  = 16*w + l15;
                    if (kvg > qg) e = 0.0f;
                }
                pk[r] = (__bf16)e;
                rs += (float)pk[r];       // sum of bf16-rounded p (matches old numerics)
            }
            *(bf16x4*)(Pw + l15*128 + ((((n*2 + (quad >> 1)) << 4)) ^ xo) + ((quad & 1) << 3)) = pk;
        }

        // ---- O += P V ----
        const char* Vc = vlds0 + cur*16384;
        #pragma unroll
        for (int ks = 0; ks < 2; ++ks) {
            bf16x8 pa = *(const bf16x8*)(Pw + l15*128 + ((((ks*4 + quad) << 4)) ^ xo));
            #pragma unroll
            for (int dt = 0; dt < 8; ++dt) {
                bf16x8 vf = *(const bf16x8*)(Vc + (dt*16 + l15)*128 + ((((ks*4 + quad) << 4)) ^ xo));
                O[dt] = __builtin_amdgcn_mfma_f32_16x16x32_bf16(pa, vf, O[dt], 0, 0, 0);
            }
        }

        __syncthreads();                 // all waves done with buf[cur]; drains t+1 loads (they ran under compute)
        cur ^= 1;
    }

    flush(qB);
}

extern "C" void kernel_launch(void* const* d_in, const int* in_sizes, int n_in,
                              void* d_out, int out_size, void* d_ws, size_t ws_size,
                              hipStream_t stream) {
    const float* Q = (const float*)d_in[0];
    const float* K = (const float*)d_in[1];
    const float* V = (const float*)d_in[2];
    float* Out = (float*)d_out;
    char* Kb = (char*)d_ws;                       // 16 MiB: 1024 tiles x 16KB
    char* Vb = (char*)d_ws + ((size_t)32 << 19);  // 16 MiB
    prep<<<dim3(8192), dim3(256), 0, stream>>>(K, V, Kb, Vb);
    fa_fwd<<<dim3(512), dim3(256), 0, stream>>>(Q, Kb, Vb, Out);
}